// Round 12
// baseline (257.183 us; speedup 1.0000x reference)
//
#include <hip/hip_runtime.h>
#include <hip/hip_bf16.h>

#define NN      200000
#define D       64
#define NTILE   12500        // NN / 16
#define BKT_SH  8            // 256 rows per bucket
#define BKT_RW  256
#define NBKT    782          // ceil(NN / 256)
#define NCHUNK  256          // edge-pass blocks (1024 threads each); epb = 12500
#define L2CAP   6656         // max edges/bucket staged in LDS (53 KB)
#define CPAD    16           // cursor padding (ints) -> one 64B line per bucket
#define RSENT   256          // sentinel r_local for pad edges

typedef __attribute__((ext_vector_type(8))) short short8;
typedef __attribute__((ext_vector_type(4))) short short4v;
typedef __attribute__((ext_vector_type(4))) float f32x4;

__device__ inline unsigned short f32_to_bf16_rne(float x) {
    unsigned u = __float_as_uint(x);
    unsigned r = u + 0x7FFFu + ((u >> 16) & 1u);
    return (unsigned short)(r >> 16);
}
__device__ inline float bf16_bits_to_f32(unsigned short h) {
    return __uint_as_float(((unsigned)h) << 16);
}
__device__ inline unsigned pack2_bf16_rne(float lo, float hi) {
    unsigned a = __float_as_uint(lo);
    unsigned b = __float_as_uint(hi);
    a = a + 0x7FFFu + ((a >> 16) & 1u);
    b = b + 0x7FFFu + ((b >> 16) & 1u);
    return (a >> 16) | (b & 0xFFFF0000u);
}
__device__ inline float bf_lo(unsigned u) { return __uint_as_float(u << 16); }
__device__ inline float bf_hi(unsigned u) { return __uint_as_float(u & 0xFFFF0000u); }

// ---------------- utility kernels ----------------
__global__ __launch_bounds__(256) void zero_f4(float4* __restrict__ p, int n4) {
    int i = blockIdx.x * blockDim.x + threadIdx.x;
    if (i < n4) p[i] = make_float4(0.f, 0.f, 0.f, 0.f);
}
__global__ __launch_bounds__(256) void zero_i(int* __restrict__ p, int n) {
    int i = blockIdx.x * blockDim.x + threadIdx.x;
    if (i < n) p[i] = 0;
}
__global__ __launch_bounds__(256) void cvt_bf16(const float2* __restrict__ in,
                                                unsigned* __restrict__ out, int n) {
    int stride = gridDim.x * blockDim.x;
    for (int i = blockIdx.x * blockDim.x + threadIdx.x; i < n; i += stride) {
        float2 v = in[i];
        out[i] = pack2_bf16_rne(v.x, v.y);
    }
}

// ---------------- pass 1: ALIGNED bucket totals (same partition as scatter) ----------------
template <int ALIGN>
__global__ __launch_bounds__(1024) void bkt_count(const int* __restrict__ rows,
                                                  int* __restrict__ tot_p,
                                                  int E, int epb) {
    __shared__ int h[NBKT];
    int t = threadIdx.x;
    for (int i = t; i < NBKT; i += 1024) h[i] = 0;
    __syncthreads();
    int start = blockIdx.x * epb;
    int end   = min(E, start + epb);
    for (int e = start + t; e < end; e += 1024)
        atomicAdd(&h[rows[e] >> BKT_SH], 1);
    __syncthreads();
    for (int i = t; i < NBKT; i += 1024) {
        int c   = h[i];
        int res = (c + ALIGN - 1) & ~(ALIGN - 1);
        if (res) atomicAdd(&tot_p[i * CPAD], res);
    }
}

// ---------------- pass 2: single-block scan over aligned bucket totals ----------------
__global__ __launch_bounds__(1024) void bkt_scan(const int* __restrict__ tot_p,
                                                 int* __restrict__ bktstart,
                                                 int* __restrict__ cursor_p) {
    __shared__ int s[1024];
    int t = threadIdx.x;
    int v = (t < NBKT) ? tot_p[t * CPAD] : 0;
    s[t] = v;
    __syncthreads();
    #pragma unroll
    for (int d = 1; d < 1024; d <<= 1) {
        int a = (t >= d) ? s[t - d] : 0;
        __syncthreads();
        s[t] += a;
        __syncthreads();
    }
    if (t < NBKT) {
        int ex = s[t] - v;
        bktstart[t] = ex;
        cursor_p[t * CPAD] = ex;
    }
    if (t == 0) bktstart[NBKT] = s[1023];
}

// ---------------- pass 3: scatter into 64B-aligned bucket runs ----------------
template <int ALIGN>
__global__ __launch_bounds__(1024) void scatter_l1(const int* __restrict__ rows,
                                                   const int* __restrict__ cols,
                                                   const float* __restrict__ vals,
                                                   int* __restrict__ cursor_p,
                                                   int2* __restrict__ packed,
                                                   int E, int epb) {
    __shared__ int h[NBKT];
    __shared__ int base[NBKT];
    int t = threadIdx.x;
    for (int i = t; i < NBKT; i += 1024) h[i] = 0;
    __syncthreads();
    int start = blockIdx.x * epb;
    int end   = min(E, start + epb);
    for (int e = start + t; e < end; e += 1024)
        atomicAdd(&h[rows[e] >> BKT_SH], 1);
    __syncthreads();
    for (int i = t; i < NBKT; i += 1024) {
        int c   = h[i];
        int res = (c + ALIGN - 1) & ~(ALIGN - 1);
        int b0  = res ? atomicAdd(&cursor_p[i * CPAD], res) : 0;
        base[i] = b0;
        for (int j = c; j < res; ++j)            // sentinel pads (never consumed)
            packed[b0 + j] = make_int2(RSENT << 18, 0);
        h[i] = 0;                                // reuse as run cursor
    }
    __syncthreads();
    for (int e = start + t; e < end; e += 1024) {
        int r = rows[e];
        int b = r >> BKT_SH;
        int p = base[b] + atomicAdd(&h[b], 1);
        packed[p] = make_int2(cols[e] | ((r & (BKT_RW - 1)) << 18),
                              __float_as_int(vals[e]));
    }
}

// ---------------- pass 4: per-bucket in-place sort to exact CSR (drops pads) ----------------
__global__ __launch_bounds__(256) void sort_l2(const int* __restrict__ bktstart,
                                               int2* __restrict__ packed,
                                               int* __restrict__ rp,
                                               int* __restrict__ rpe) {
    __shared__ int2 sm[L2CAP];
    __shared__ int  cnt[BKT_RW];
    __shared__ int  cur[BKT_RW];
    int b = blockIdx.x;
    int s = bktstart[b];
    int e = bktstart[b + 1];
    int n = e - s;
    if (n > L2CAP) n = L2CAP;
    int t = threadIdx.x;
    cnt[t] = 0;
    __syncthreads();
    for (int i = t; i < n; i += 256) {
        int2 v = packed[s + i];
        sm[i] = v;
        int r = (v.x >> 18) & 0x1FF;
        if (r < BKT_RW) atomicAdd(&cnt[r], 1);
    }
    __syncthreads();
    #pragma unroll
    for (int d = 1; d < BKT_RW; d <<= 1) {
        int a = (t >= d) ? cnt[t - d] : 0;
        __syncthreads();
        cnt[t] += a;
        __syncthreads();
    }
    {
        int ex = t ? cnt[t - 1] : 0;
        cur[t] = ex;
        int g = (b << BKT_SH) + t;
        if (g < NN) { rp[g] = s + ex; rpe[g] = s + cnt[t]; }
    }
    __syncthreads();
    for (int i = t; i < n; i += 256) {
        int2 v = sm[i];
        int  r = (v.x >> 18) & 0x1FF;
        if (r < BKT_RW) {
            int p = atomicAdd(&cur[r], 1);
            packed[s + p] = make_int2(v.x & 0x3FFFF, v.y);
        }
    }
}

// ---------------- gather macro body (4 rows/wave, quarter-wave per row) ----------------
#define GATHER_BODY(rpv, rpev, packedv, einv)                                      \
    float ax = 0.f, ay = 0.f, az = 0.f, aw = 0.f;                                  \
    {                                                                              \
        int s_ = rpv, e_ = rpev;                                                   \
        for (int base_ = s_; base_ < e_; base_ += 16) {                            \
            int cnt = e_ - base_; if (cnt > 16) cnt = 16;                          \
            int2 ev = make_int2(0, 0);                                             \
            if (l < cnt) ev = packedv[base_ + l];                                  \
            int k = 0;                                                             \
            for (; k + 4 <= cnt; k += 4) {                                         \
                int   c0 = __shfl(ev.x, k,     16), c1 = __shfl(ev.x, k + 1, 16);  \
                int   c2 = __shfl(ev.x, k + 2, 16), c3 = __shfl(ev.x, k + 3, 16);  \
                float v0 = __int_as_float(__shfl(ev.y, k,     16));                \
                float v1 = __int_as_float(__shfl(ev.y, k + 1, 16));                \
                float v2 = __int_as_float(__shfl(ev.y, k + 2, 16));                \
                float v3 = __int_as_float(__shfl(ev.y, k + 3, 16));                \
                uint2 g0 = einv[c0 * 16 + l];                                      \
                uint2 g1 = einv[c1 * 16 + l];                                      \
                uint2 g2 = einv[c2 * 16 + l];                                      \
                uint2 g3 = einv[c3 * 16 + l];                                      \
                ax += v0 * bf_lo(g0.x); ay += v0 * bf_hi(g0.x);                    \
                az += v0 * bf_lo(g0.y); aw += v0 * bf_hi(g0.y);                    \
                ax += v1 * bf_lo(g1.x); ay += v1 * bf_hi(g1.x);                    \
                az += v1 * bf_lo(g1.y); aw += v1 * bf_hi(g1.y);                    \
                ax += v2 * bf_lo(g2.x); ay += v2 * bf_hi(g2.x);                    \
                az += v2 * bf_lo(g2.y); aw += v2 * bf_hi(g2.y);                    \
                ax += v3 * bf_lo(g3.x); ay += v3 * bf_hi(g3.x);                    \
                az += v3 * bf_lo(g3.y); aw += v3 * bf_hi(g3.y);                    \
            }                                                                      \
            for (; k < cnt; ++k) {                                                 \
                int   c0 = __shfl(ev.x, k, 16);                                    \
                float v0 = __int_as_float(__shfl(ev.y, k, 16));                    \
                uint2 g0 = einv[c0 * 16 + l];                                      \
                ax += v0 * bf_lo(g0.x); ay += v0 * bf_hi(g0.x);                    \
                az += v0 * bf_lo(g0.y); aw += v0 * bf_hi(g0.y);                    \
            }                                                                      \
        }                                                                          \
    }

// ---------------- hop-1 gather SpMM: bf16 out ----------------
__global__ __launch_bounds__(256) void spmm_q1(const int* __restrict__ rp,
                                               const int* __restrict__ rpe,
                                               const int2* __restrict__ packed,
                                               const uint2* __restrict__ ein,
                                               uint2* __restrict__ out_bf, int n) {
    int wave = (blockIdx.x * 256 + threadIdx.x) >> 6;
    int lane = threadIdx.x & 63;
    int l    = lane & 15;
    int row  = wave * 4 + (lane >> 4);
    if (row >= n) return;
    GATHER_BODY(rp[row], rpe[row], packed, ein)
    out_bf[(size_t)row * 16 + l] = make_uint2(pack2_bf16_rne(ax, ay), pack2_bf16_rne(az, aw));
}

// ---------------- hop-2 gather SpMM fused with MLP+LN epilogue ----------------
// Block = 4 waves x 4 rows = 16 rows = one MFMA tile. Gather -> LDS tile,
// __syncthreads, wave 0 runs the MLP+LN tile and stores final f32 rows.
__global__ __launch_bounds__(256) void spmm_mlp(const int* __restrict__ rp,
                                                const int* __restrict__ rpe,
                                                const int2* __restrict__ packed,
                                                const uint2* __restrict__ ein,
                                                float* __restrict__ out,
                                                const float* __restrict__ Ws,
                                                const float* __restrict__ bs,
                                                const float* __restrict__ gamma,
                                                const float* __restrict__ beta) {
    __shared__ unsigned short wlds[2][64][72];   // bf16 W, padded rows
    __shared__ float tb[16][68];                 // block tile, padded rows

    int t    = threadIdx.x;
    int lane = t & 63;
    int wv   = t >> 6;
    int l    = lane & 15;
    int q    = lane >> 4;

    // stage W (both layers) into LDS as bf16: 256 threads x 4 = 1024/sweep
    for (int i = t * 4; i < 2 * 64 * 64; i += 1024) {
        float4 f = *(const float4*)(Ws + i);
        int ly = i >> 12, r = (i >> 6) & 63, c = i & 63;
        short4v s4;
        s4[0] = (short)f32_to_bf16_rne(f.x);
        s4[1] = (short)f32_to_bf16_rne(f.y);
        s4[2] = (short)f32_to_bf16_rne(f.z);
        s4[3] = (short)f32_to_bf16_rne(f.w);
        *(short4v*)&wlds[ly][r][c] = s4;
    }

    int row_local = wv * 4 + q;
    int row = blockIdx.x * 16 + row_local;       // grid = NN/16 exact
    GATHER_BODY(rp[row], rpe[row], packed, ein)
    *(float4*)&tb[row_local][l * 4] = make_float4(ax, ay, az, aw);
    __syncthreads();

    if (wv == 0) {
        int fr = lane & 15;
        int fq = lane >> 4;
        float bia[2][4], gam[4], bet[4];
        #pragma unroll
        for (int nt = 0; nt < 4; ++nt) {
            bia[0][nt] = bs[nt * 16 + fr];
            bia[1][nt] = bs[64 + nt * 16 + fr];
            gam[nt]    = gamma[nt * 16 + fr];
            bet[nt]    = beta[nt * 16 + fr];
        }

        #pragma unroll
        for (int ly = 0; ly < 2; ++ly) {
            short8 xh[2], xl[2];
            #pragma unroll
            for (int kk = 0; kk < 2; ++kk) {
                const float* s = &tb[fr][kk * 32 + fq * 8];
                float4 a = *(const float4*)s;
                float4 b4 = *(const float4*)(s + 4);
                float v[8] = {a.x, a.y, a.z, a.w, b4.x, b4.y, b4.z, b4.w};
                #pragma unroll
                for (int j = 0; j < 8; ++j) {
                    unsigned short hh = f32_to_bf16_rne(v[j]);
                    xh[kk][j] = (short)hh;
                    xl[kk][j] = (short)f32_to_bf16_rne(v[j] - bf16_bits_to_f32(hh));
                }
            }
            f32x4 acc[4];
            #pragma unroll
            for (int nt = 0; nt < 4; ++nt) {
                float bb = bia[ly][nt];
                acc[nt] = f32x4{bb, bb, bb, bb};
                #pragma unroll
                for (int kk = 0; kk < 2; ++kk) {
                    short8 w8 = *(const short8*)&wlds[ly][nt * 16 + fr][kk * 32 + fq * 8];
                    acc[nt] = __builtin_amdgcn_mfma_f32_16x16x32_bf16(xl[kk], w8, acc[nt], 0, 0, 0);
                    acc[nt] = __builtin_amdgcn_mfma_f32_16x16x32_bf16(xh[kk], w8, acc[nt], 0, 0, 0);
                }
            }
            #pragma unroll
            for (int nt = 0; nt < 4; ++nt)
                #pragma unroll
                for (int j = 0; j < 4; ++j) {
                    float* cell = &tb[fq * 4 + j][nt * 16 + fr];
                    *cell = fmaxf(acc[nt][j], 0.f) + *cell;
                }
        }

        // LayerNorm over the 16-row tile
        float y2[4][4], sm[4], sq[4];
        #pragma unroll
        for (int j = 0; j < 4; ++j) { sm[j] = 0.f; sq[j] = 0.f; }
        #pragma unroll
        for (int nt = 0; nt < 4; ++nt)
            #pragma unroll
            for (int j = 0; j < 4; ++j) {
                float v = tb[fq * 4 + j][nt * 16 + fr];
                y2[nt][j] = v;
                sm[j] += v; sq[j] += v * v;
            }
        #pragma unroll
        for (int off = 1; off < 16; off <<= 1) {
            #pragma unroll
            for (int j = 0; j < 4; ++j) {
                sm[j] += __shfl_xor(sm[j], off);
                sq[j] += __shfl_xor(sq[j], off);
            }
        }
        #pragma unroll
        for (int j = 0; j < 4; ++j) {
            float mu  = sm[j] * (1.f / 64.f);
            float var = sq[j] * (1.f / 64.f) - mu * mu;
            float rs  = rsqrtf(var + 1e-5f);
            #pragma unroll
            for (int nt = 0; nt < 4; ++nt)
                tb[fq * 4 + j][nt * 16 + fr] = (y2[nt][j] - mu) * rs * gam[nt] + bet[nt];
        }

        // coalesced stage-out (wave 0: 64 lanes x 4 float4)
        float* base = out + (size_t)blockIdx.x * 1024;
        #pragma unroll
        for (int it = 0; it < 4; ++it) {
            int idx = it * 256 + lane * 4;
            *(float4*)(base + idx) = *(const float4*)&tb[idx >> 6][idx & 63];
        }
    }
}

// ---------------- fallback scatter SpMM (atomic path) ----------------
__global__ __launch_bounds__(256) void spmm_scatter(const int* __restrict__ rows,
                                                    const int* __restrict__ cols,
                                                    const float* __restrict__ vals,
                                                    const float* __restrict__ ein,
                                                    float* __restrict__ eout, int E) {
    int gid  = blockIdx.x * blockDim.x + threadIdx.x;
    int wid  = gid >> 6;
    int lane = threadIdx.x & 63;
    int nw   = (gridDim.x * blockDim.x) >> 6;
    for (int e = wid; e < E; e += nw) {
        int   r = rows[e];
        int   c = cols[e];
        float v = vals[e];
        float x = ein[(size_t)c * D + lane];
        unsafeAtomicAdd(&eout[(size_t)r * D + lane], v * x);
    }
}

// ---------------- standalone MFMA MLP+LN (fallback paths only) ----------------
__global__ __launch_bounds__(256) void mlp_v2(float* __restrict__ e,
                                              const float* __restrict__ Ws,
                                              const float* __restrict__ bs,
                                              const float* __restrict__ gamma,
                                              const float* __restrict__ beta) {
    __shared__ unsigned short wlds[2][64][72];
    __shared__ float tb[4][16][68];

    int t    = threadIdx.x;
    int wv   = t >> 6;
    int lane = t & 63;
    int fr   = t & 15;
    int fq   = lane >> 4;

    for (int i = t * 4; i < 2 * 64 * 64; i += 1024) {
        float4 f = *(const float4*)(Ws + i);
        int l = i >> 12, r = (i >> 6) & 63, c = i & 63;
        short4v s4;
        s4[0] = (short)f32_to_bf16_rne(f.x);
        s4[1] = (short)f32_to_bf16_rne(f.y);
        s4[2] = (short)f32_to_bf16_rne(f.z);
        s4[3] = (short)f32_to_bf16_rne(f.w);
        *(short4v*)&wlds[l][r][c] = s4;
    }
    __syncthreads();

    float bia[2][4], gam[4], bet[4];
    #pragma unroll
    for (int nt = 0; nt < 4; ++nt) {
        bia[0][nt] = bs[nt * 16 + fr];
        bia[1][nt] = bs[64 + nt * 16 + fr];
        gam[nt]    = gamma[nt * 16 + fr];
        bet[nt]    = beta[nt * 16 + fr];
    }

    float (*tw)[68] = tb[wv];

    for (int tile = blockIdx.x * 4 + wv; tile < NTILE; tile += gridDim.x * 4) {
        float* base = e + (size_t)tile * 1024;
        #pragma unroll
        for (int it = 0; it < 4; ++it) {
            int idx = it * 256 + lane * 4;
            *(float4*)&tw[idx >> 6][idx & 63] = *(const float4*)(base + idx);
        }
        #pragma unroll
        for (int l = 0; l < 2; ++l) {
            short8 xh[2], xl[2];
            #pragma unroll
            for (int kk = 0; kk < 2; ++kk) {
                const float* s = &tw[fr][kk * 32 + fq * 8];
                float4 a = *(const float4*)s;
                float4 b4 = *(const float4*)(s + 4);
                float v[8] = {a.x, a.y, a.z, a.w, b4.x, b4.y, b4.z, b4.w};
                #pragma unroll
                for (int j = 0; j < 8; ++j) {
                    unsigned short hh = f32_to_bf16_rne(v[j]);
                    xh[kk][j] = (short)hh;
                    xl[kk][j] = (short)f32_to_bf16_rne(v[j] - bf16_bits_to_f32(hh));
                }
            }
            f32x4 acc[4];
            #pragma unroll
            for (int nt = 0; nt < 4; ++nt) {
                float bb = bia[l][nt];
                acc[nt] = f32x4{bb, bb, bb, bb};
                #pragma unroll
                for (int kk = 0; kk < 2; ++kk) {
                    short8 w8 = *(const short8*)&wlds[l][nt * 16 + fr][kk * 32 + fq * 8];
                    acc[nt] = __builtin_amdgcn_mfma_f32_16x16x32_bf16(xl[kk], w8, acc[nt], 0, 0, 0);
                    acc[nt] = __builtin_amdgcn_mfma_f32_16x16x32_bf16(xh[kk], w8, acc[nt], 0, 0, 0);
                }
            }
            #pragma unroll
            for (int nt = 0; nt < 4; ++nt)
                #pragma unroll
                for (int j = 0; j < 4; ++j) {
                    float* cell = &tw[fq * 4 + j][nt * 16 + fr];
                    *cell = fmaxf(acc[nt][j], 0.f) + *cell;
                }
        }
        float y2[4][4], sm[4], sq[4];
        #pragma unroll
        for (int j = 0; j < 4; ++j) { sm[j] = 0.f; sq[j] = 0.f; }
        #pragma unroll
        for (int nt = 0; nt < 4; ++nt)
            #pragma unroll
            for (int j = 0; j < 4; ++j) {
                float v = tw[fq * 4 + j][nt * 16 + fr];
                y2[nt][j] = v;
                sm[j] += v; sq[j] += v * v;
            }
        #pragma unroll
        for (int off = 1; off < 16; off <<= 1) {
            #pragma unroll
            for (int j = 0; j < 4; ++j) {
                sm[j] += __shfl_xor(sm[j], off);
                sq[j] += __shfl_xor(sq[j], off);
            }
        }
        #pragma unroll
        for (int j = 0; j < 4; ++j) {
            float mu  = sm[j] * (1.f / 64.f);
            float var = sq[j] * (1.f / 64.f) - mu * mu;
            float rs  = rsqrtf(var + 1e-5f);
            #pragma unroll
            for (int nt = 0; nt < 4; ++nt)
                tw[fq * 4 + j][nt * 16 + fr] = (y2[nt][j] - mu) * rs * gam[nt] + bet[nt];
        }
        #pragma unroll
        for (int it = 0; it < 4; ++it) {
            int idx = it * 256 + lane * 4;
            *(float4*)(base + idx) = *(const float4*)&tw[idx >> 6][idx & 63];
        }
    }
}

template <int ALIGN>
static void run_csr(const int* rows, const int* cols, const float* vals,
                    const float* ini, float* out, char* w, int E, size_t packed_cap,
                    const float* Ws, const float* bs, const float* gamma,
                    const float* beta, hipStream_t stream) {
    size_t inibf_b  = (size_t)NN * 32 * 4;
    size_t e1bf_b   = inibf_b;
    size_t packed_b = packed_cap * 8;
    size_t rp_b     = (((size_t)NN + 1) * 4 + 63) & ~(size_t)63;
    size_t rpe_b    = (ALIGN > 1) ? rp_b : 0;
    size_t bsrt_b   = (((size_t)NBKT + 1) * 4 + 63) & ~(size_t)63;
    size_t pad_b    = (size_t)NBKT * CPAD * 4;

    unsigned* ini_bf   = (unsigned*)w;  w += inibf_b;
    unsigned* e1_bf    = (unsigned*)w;  w += e1bf_b;
    int2*     packed   = (int2*)w;      w += packed_b;
    int*      rp       = (int*)w;       w += rp_b;
    int*      rpe      = (ALIGN > 1) ? (int*)w : rp + 1;  w += rpe_b;
    int*      bktstart = (int*)w;       w += bsrt_b;
    int*      tot_p    = (int*)w;       w += pad_b;
    int*      cursor_p = (int*)w;

    int epb = (E + NCHUNK - 1) / NCHUNK;
    cvt_bf16<<<2048, 256, 0, stream>>>((const float2*)ini, ini_bf, NN * 32);
    zero_i<<<(NBKT * CPAD + 255) / 256, 256, 0, stream>>>(tot_p, NBKT * CPAD);
    bkt_count<ALIGN><<<NCHUNK, 1024, 0, stream>>>(rows, tot_p, E, epb);
    bkt_scan<<<1, 1024, 0, stream>>>(tot_p, bktstart, cursor_p);
    scatter_l1<ALIGN><<<NCHUNK, 1024, 0, stream>>>(rows, cols, vals, cursor_p, packed, E, epb);
    sort_l2<<<NBKT, 256, 0, stream>>>(bktstart, packed, rp, rpe);

    spmm_q1<<<NTILE, 256, 0, stream>>>(rp, rpe, packed, (const uint2*)ini_bf,
                                       (uint2*)e1_bf, NN);
    spmm_mlp<<<NTILE, 256, 0, stream>>>(rp, rpe, packed, (const uint2*)e1_bf,
                                        out, Ws, bs, gamma, beta);
}

extern "C" void kernel_launch(void* const* d_in, const int* in_sizes, int n_in,
                              void* d_out, int out_size, void* d_ws, size_t ws_size,
                              hipStream_t stream) {
    const int*   rows  = (const int*)d_in[0];
    const int*   cols  = (const int*)d_in[1];
    const float* vals  = (const float*)d_in[2];
    const float* ini   = (const float*)d_in[3];
    const float* Ws    = (const float*)d_in[4];
    const float* bs    = (const float*)d_in[5];
    const float* gamma = (const float*)d_in[6];
    const float* beta  = (const float*)d_in[7];
    float* out = (float*)d_out;
    int E = in_sizes[0];

    size_t inibf_b = (size_t)NN * 32 * 4;
    size_t rp_b    = (((size_t)NN + 1) * 4 + 63) & ~(size_t)63;
    size_t bsrt_b  = (((size_t)NBKT + 1) * 4 + 63) & ~(size_t)63;
    size_t pad_b   = (size_t)NBKT * CPAD * 4;
    size_t cap8    = (size_t)E + (size_t)NBKT * NCHUNK * 7;   // worst-case pads
    size_t cap1    = (size_t)E;
    size_t need8   = 2 * inibf_b + cap8 * 8 + 2 * rp_b + bsrt_b + 2 * pad_b;
    size_t need1   = 2 * inibf_b + cap1 * 8 + rp_b + bsrt_b + 2 * pad_b;

    if (ws_size >= need8) {
        run_csr<8>(rows, cols, vals, ini, out, (char*)d_ws, E, cap8,
                   Ws, bs, gamma, beta, stream);
    } else if (ws_size >= need1) {
        run_csr<1>(rows, cols, vals, ini, out, (char*)d_ws, E, cap1,
                   Ws, bs, gamma, beta, stream);
        // MLP handled inside run_csr via spmm_mlp
    } else {
        float* e1 = (float*)d_ws;
        int n4 = out_size / 4;
        int zb = (n4 + 255) / 256;
        zero_f4<<<zb, 256, 0, stream>>>((float4*)e1,  n4);
        zero_f4<<<zb, 256, 0, stream>>>((float4*)out, n4);
        spmm_scatter<<<12800, 256, 0, stream>>>(rows, cols, vals, ini, e1, E);
        spmm_scatter<<<12800, 256, 0, stream>>>(rows, cols, vals, e1, out, E);
        mlp_v2<<<512, 256, 0, stream>>>(out, Ws, bs, gamma, beta);
    }
}

// Round 13
// 243.660 us; speedup vs baseline: 1.0555x; 1.0555x over previous
//
#include <hip/hip_runtime.h>
#include <hip/hip_bf16.h>

#define NN      200000
#define D       64
#define NTILE   12500        // NN / 16
#define BKT_SH  8            // 256 rows per bucket
#define BKT_RW  256
#define NBKT    782          // ceil(NN / 256)
#define L2CAP   7680         // max edges/bucket staged in LDS (61.4 KB)
#define CPAD    16           // cursor padding (ints) -> one 64B line per bucket
#define RSENT   256          // sentinel r_local for pad edges

typedef __attribute__((ext_vector_type(8))) short short8;
typedef __attribute__((ext_vector_type(4))) short short4v;
typedef __attribute__((ext_vector_type(4))) float f32x4;

__device__ inline unsigned short f32_to_bf16_rne(float x) {
    unsigned u = __float_as_uint(x);
    unsigned r = u + 0x7FFFu + ((u >> 16) & 1u);
    return (unsigned short)(r >> 16);
}
__device__ inline float bf16_bits_to_f32(unsigned short h) {
    return __uint_as_float(((unsigned)h) << 16);
}
__device__ inline unsigned pack2_bf16_rne(float lo, float hi) {
    unsigned a = __float_as_uint(lo);
    unsigned b = __float_as_uint(hi);
    a = a + 0x7FFFu + ((a >> 16) & 1u);
    b = b + 0x7FFFu + ((b >> 16) & 1u);
    return (a >> 16) | (b & 0xFFFF0000u);
}
__device__ inline float bf_lo(unsigned u) { return __uint_as_float(u << 16); }
__device__ inline float bf_hi(unsigned u) { return __uint_as_float(u & 0xFFFF0000u); }

// ---------------- utility kernels ----------------
__global__ __launch_bounds__(256) void zero_f4(float4* __restrict__ p, int n4) {
    int i = blockIdx.x * blockDim.x + threadIdx.x;
    if (i < n4) p[i] = make_float4(0.f, 0.f, 0.f, 0.f);
}
__global__ __launch_bounds__(256) void zero_i(int* __restrict__ p, int n) {
    int i = blockIdx.x * blockDim.x + threadIdx.x;
    if (i < n) p[i] = 0;
}
__global__ __launch_bounds__(256) void cvt_bf16(const float2* __restrict__ in,
                                                unsigned* __restrict__ out, int n) {
    int stride = gridDim.x * blockDim.x;
    for (int i = blockIdx.x * blockDim.x + threadIdx.x; i < n; i += stride) {
        float2 v = in[i];
        out[i] = pack2_bf16_rne(v.x, v.y);
    }
}

// ---------------- pass 1: ALIGNED bucket totals (same partition as scatter) ----------------
template <int ALIGN>
__global__ __launch_bounds__(1024) void bkt_count(const int* __restrict__ rows,
                                                  int* __restrict__ tot_p,
                                                  int E, int epb) {
    __shared__ int h[NBKT];
    int t = threadIdx.x;
    for (int i = t; i < NBKT; i += 1024) h[i] = 0;
    __syncthreads();
    int start = blockIdx.x * epb;
    int end   = min(E, start + epb);
    for (int e = start + t; e < end; e += 1024)
        atomicAdd(&h[rows[e] >> BKT_SH], 1);
    __syncthreads();
    for (int i = t; i < NBKT; i += 1024) {
        int c   = h[i];
        int res = (c + ALIGN - 1) & ~(ALIGN - 1);
        if (res) atomicAdd(&tot_p[i * CPAD], res);
    }
}

// ---------------- pass 2: single-block scan over aligned bucket totals ----------------
__global__ __launch_bounds__(1024) void bkt_scan(const int* __restrict__ tot_p,
                                                 int* __restrict__ bktstart,
                                                 int* __restrict__ cursor_p) {
    __shared__ int s[1024];
    int t = threadIdx.x;
    int v = (t < NBKT) ? tot_p[t * CPAD] : 0;
    s[t] = v;
    __syncthreads();
    #pragma unroll
    for (int d = 1; d < 1024; d <<= 1) {
        int a = (t >= d) ? s[t - d] : 0;
        __syncthreads();
        s[t] += a;
        __syncthreads();
    }
    if (t < NBKT) {
        int ex = s[t] - v;
        bktstart[t] = ex;
        cursor_p[t * CPAD] = ex;
    }
    if (t == 0) bktstart[NBKT] = s[1023];
}

// ---------------- pass 3: scatter into 64B-aligned bucket runs ----------------
template <int ALIGN>
__global__ __launch_bounds__(1024) void scatter_l1(const int* __restrict__ rows,
                                                   const int* __restrict__ cols,
                                                   const float* __restrict__ vals,
                                                   int* __restrict__ cursor_p,
                                                   int2* __restrict__ packed,
                                                   int E, int epb) {
    __shared__ int h[NBKT];
    __shared__ int base[NBKT];
    int t = threadIdx.x;
    for (int i = t; i < NBKT; i += 1024) h[i] = 0;
    __syncthreads();
    int start = blockIdx.x * epb;
    int end   = min(E, start + epb);
    for (int e = start + t; e < end; e += 1024)
        atomicAdd(&h[rows[e] >> BKT_SH], 1);
    __syncthreads();
    for (int i = t; i < NBKT; i += 1024) {
        int c   = h[i];
        int res = (c + ALIGN - 1) & ~(ALIGN - 1);
        int b0  = res ? atomicAdd(&cursor_p[i * CPAD], res) : 0;
        base[i] = b0;
        for (int j = c; j < res; ++j)            // sentinel pads (never consumed)
            packed[b0 + j] = make_int2(RSENT << 18, 0);
        h[i] = 0;                                // reuse as run cursor
    }
    __syncthreads();
    for (int e = start + t; e < end; e += 1024) {
        int r = rows[e];
        int b = r >> BKT_SH;
        int p = base[b] + atomicAdd(&h[b], 1);
        packed[p] = make_int2(cols[e] | ((r & (BKT_RW - 1)) << 18),
                              __float_as_int(vals[e]));
    }
}

// ---------------- pass 4: per-bucket in-place sort to exact CSR (drops pads) ----------------
__global__ __launch_bounds__(256) void sort_l2(const int* __restrict__ bktstart,
                                               int2* __restrict__ packed,
                                               int* __restrict__ rp,
                                               int* __restrict__ rpe) {
    __shared__ int2 sm[L2CAP];
    __shared__ int  cnt[BKT_RW];
    __shared__ int  cur[BKT_RW];
    int b = blockIdx.x;
    int s = bktstart[b];
    int e = bktstart[b + 1];
    int n = e - s;
    if (n > L2CAP) n = L2CAP;
    int t = threadIdx.x;
    cnt[t] = 0;
    __syncthreads();
    for (int i = t; i < n; i += 256) {
        int2 v = packed[s + i];
        sm[i] = v;
        int r = (v.x >> 18) & 0x1FF;
        if (r < BKT_RW) atomicAdd(&cnt[r], 1);
    }
    __syncthreads();
    #pragma unroll
    for (int d = 1; d < BKT_RW; d <<= 1) {
        int a = (t >= d) ? cnt[t - d] : 0;
        __syncthreads();
        cnt[t] += a;
        __syncthreads();
    }
    {
        int ex = t ? cnt[t - 1] : 0;
        cur[t] = ex;
        int g = (b << BKT_SH) + t;
        if (g < NN) { rp[g] = s + ex; rpe[g] = s + cnt[t]; }
    }
    __syncthreads();
    for (int i = t; i < n; i += 256) {
        int2 v = sm[i];
        int  r = (v.x >> 18) & 0x1FF;
        if (r < BKT_RW) {
            int p = atomicAdd(&cur[r], 1);
            packed[s + p] = make_int2(v.x & 0x3FFFF, v.y);
        }
    }
}

// ---------------- gather SpMM, 4 rows/wave, quarter-wave per row, bf16 out ----------------
__global__ __launch_bounds__(256) void spmm_g(const int* __restrict__ rp,
                                              const int* __restrict__ rpe,
                                              const int2* __restrict__ packed,
                                              const uint2* __restrict__ ein,
                                              uint2* __restrict__ out_bf, int n) {
    int wave = (blockIdx.x * 256 + threadIdx.x) >> 6;
    int lane = threadIdx.x & 63;
    int l    = lane & 15;
    int row  = wave * 4 + (lane >> 4);
    if (row >= n) return;

    float ax = 0.f, ay = 0.f, az = 0.f, aw = 0.f;
    int s = rp[row], e = rpe[row];
    for (int base = s; base < e; base += 16) {
        int cnt = e - base; if (cnt > 16) cnt = 16;
        int2 ev = make_int2(0, 0);
        if (l < cnt) ev = packed[base + l];
        int k = 0;
        for (; k + 4 <= cnt; k += 4) {
            int   c0 = __shfl(ev.x, k,     16), c1 = __shfl(ev.x, k + 1, 16);
            int   c2 = __shfl(ev.x, k + 2, 16), c3 = __shfl(ev.x, k + 3, 16);
            float v0 = __int_as_float(__shfl(ev.y, k,     16));
            float v1 = __int_as_float(__shfl(ev.y, k + 1, 16));
            float v2 = __int_as_float(__shfl(ev.y, k + 2, 16));
            float v3 = __int_as_float(__shfl(ev.y, k + 3, 16));
            uint2 g0 = ein[c0 * 16 + l];
            uint2 g1 = ein[c1 * 16 + l];
            uint2 g2 = ein[c2 * 16 + l];
            uint2 g3 = ein[c3 * 16 + l];
            ax += v0 * bf_lo(g0.x); ay += v0 * bf_hi(g0.x);
            az += v0 * bf_lo(g0.y); aw += v0 * bf_hi(g0.y);
            ax += v1 * bf_lo(g1.x); ay += v1 * bf_hi(g1.x);
            az += v1 * bf_lo(g1.y); aw += v1 * bf_hi(g1.y);
            ax += v2 * bf_lo(g2.x); ay += v2 * bf_hi(g2.x);
            az += v2 * bf_lo(g2.y); aw += v2 * bf_hi(g2.y);
            ax += v3 * bf_lo(g3.x); ay += v3 * bf_hi(g3.x);
            az += v3 * bf_lo(g3.y); aw += v3 * bf_hi(g3.y);
        }
        for (; k < cnt; ++k) {
            int   c0 = __shfl(ev.x, k, 16);
            float v0 = __int_as_float(__shfl(ev.y, k, 16));
            uint2 g0 = ein[c0 * 16 + l];
            ax += v0 * bf_lo(g0.x); ay += v0 * bf_hi(g0.x);
            az += v0 * bf_lo(g0.y); aw += v0 * bf_hi(g0.y);
        }
    }
    out_bf[(size_t)row * 16 + l] = make_uint2(pack2_bf16_rne(ax, ay), pack2_bf16_rne(az, aw));
}

// ---------------- fallback scatter SpMM (atomic path) ----------------
__global__ __launch_bounds__(256) void spmm_scatter(const int* __restrict__ rows,
                                                    const int* __restrict__ cols,
                                                    const float* __restrict__ vals,
                                                    const float* __restrict__ ein,
                                                    float* __restrict__ eout, int E) {
    int gid  = blockIdx.x * blockDim.x + threadIdx.x;
    int wid  = gid >> 6;
    int lane = threadIdx.x & 63;
    int nw   = (gridDim.x * blockDim.x) >> 6;
    for (int e = wid; e < E; e += nw) {
        int   r = rows[e];
        int   c = cols[e];
        float v = vals[e];
        float x = ein[(size_t)c * D + lane];
        unsafeAtomicAdd(&eout[(size_t)r * D + lane], v * x);
    }
}

// ---------------- MFMA fused MLP+LN: W in LDS, coalesced LDS-staged tiles ----------------
// IN_BF16=1: read bf16 tile from in_bf, write f32 to out (separate buffers);
//            layer-1 x is exactly bf16 -> skip the zero x-lo MFMA.
// IN_BF16=0: f32 in-place on out (fallback path).
template <int IN_BF16>
__global__ __launch_bounds__(256) void mlp_v2(const uint2* __restrict__ in_bf,
                                              float* __restrict__ out,
                                              const float* __restrict__ Ws,
                                              const float* __restrict__ bs,
                                              const float* __restrict__ gamma,
                                              const float* __restrict__ beta) {
    __shared__ unsigned short wlds[2][64][72];
    __shared__ float tb[4][16][68];

    int t    = threadIdx.x;
    int wv   = t >> 6;
    int lane = t & 63;
    int fr   = t & 15;
    int fq   = lane >> 4;

    for (int i = t * 4; i < 2 * 64 * 64; i += 1024) {
        float4 f = *(const float4*)(Ws + i);
        int l = i >> 12, r = (i >> 6) & 63, c = i & 63;
        short4v s4;
        s4[0] = (short)f32_to_bf16_rne(f.x);
        s4[1] = (short)f32_to_bf16_rne(f.y);
        s4[2] = (short)f32_to_bf16_rne(f.z);
        s4[3] = (short)f32_to_bf16_rne(f.w);
        *(short4v*)&wlds[l][r][c] = s4;
    }
    __syncthreads();

    float bia[2][4], gam[4], bet[4];
    #pragma unroll
    for (int nt = 0; nt < 4; ++nt) {
        bia[0][nt] = bs[nt * 16 + fr];
        bia[1][nt] = bs[64 + nt * 16 + fr];
        gam[nt]    = gamma[nt * 16 + fr];
        bet[nt]    = beta[nt * 16 + fr];
    }

    float (*tw)[68] = tb[wv];

    for (int tile = blockIdx.x * 4 + wv; tile < NTILE; tile += gridDim.x * 4) {
        float* baseo = out + (size_t)tile * 1024;

        // stage-in
        if (IN_BF16) {
            const uint2* bi = in_bf + (size_t)tile * 256;
            #pragma unroll
            for (int it = 0; it < 4; ++it) {
                int idx = it * 64 + lane;           // uint2 index within tile
                uint2 u = bi[idx];
                int r = idx >> 4, c = (idx & 15) * 4;
                tw[r][c]     = bf_lo(u.x);
                tw[r][c + 1] = bf_hi(u.x);
                tw[r][c + 2] = bf_lo(u.y);
                tw[r][c + 3] = bf_hi(u.y);
            }
        } else {
            #pragma unroll
            for (int it = 0; it < 4; ++it) {
                int idx = it * 256 + lane * 4;
                *(float4*)&tw[idx >> 6][idx & 63] = *(const float4*)(baseo + idx);
            }
        }

        #pragma unroll
        for (int l = 0; l < 2; ++l) {
            short8 xh[2], xl[2];
            #pragma unroll
            for (int kk = 0; kk < 2; ++kk) {
                const float* s = &tw[fr][kk * 32 + fq * 8];
                float4 a = *(const float4*)s;
                float4 b4 = *(const float4*)(s + 4);
                float v[8] = {a.x, a.y, a.z, a.w, b4.x, b4.y, b4.z, b4.w};
                #pragma unroll
                for (int j = 0; j < 8; ++j) {
                    unsigned short hh = f32_to_bf16_rne(v[j]);
                    xh[kk][j] = (short)hh;
                    xl[kk][j] = (short)f32_to_bf16_rne(v[j] - bf16_bits_to_f32(hh));
                }
            }
            f32x4 acc[4];
            #pragma unroll
            for (int nt = 0; nt < 4; ++nt) {
                float bb = bia[l][nt];
                acc[nt] = f32x4{bb, bb, bb, bb};
                #pragma unroll
                for (int kk = 0; kk < 2; ++kk) {
                    short8 w8 = *(const short8*)&wlds[l][nt * 16 + fr][kk * 32 + fq * 8];
                    if (!(IN_BF16 && l == 0))   // layer-1 x-lo is exactly 0 when input is bf16
                        acc[nt] = __builtin_amdgcn_mfma_f32_16x16x32_bf16(xl[kk], w8, acc[nt], 0, 0, 0);
                    acc[nt] = __builtin_amdgcn_mfma_f32_16x16x32_bf16(xh[kk], w8, acc[nt], 0, 0, 0);
                }
            }
            #pragma unroll
            for (int nt = 0; nt < 4; ++nt)
                #pragma unroll
                for (int j = 0; j < 4; ++j) {
                    float* cell = &tw[fq * 4 + j][nt * 16 + fr];
                    *cell = fmaxf(acc[nt][j], 0.f) + *cell;
                }
        }

        float y2[4][4], sm[4], sq[4];
        #pragma unroll
        for (int j = 0; j < 4; ++j) { sm[j] = 0.f; sq[j] = 0.f; }
        #pragma unroll
        for (int nt = 0; nt < 4; ++nt)
            #pragma unroll
            for (int j = 0; j < 4; ++j) {
                float v = tw[fq * 4 + j][nt * 16 + fr];
                y2[nt][j] = v;
                sm[j] += v; sq[j] += v * v;
            }
        #pragma unroll
        for (int off = 1; off < 16; off <<= 1) {
            #pragma unroll
            for (int j = 0; j < 4; ++j) {
                sm[j] += __shfl_xor(sm[j], off);
                sq[j] += __shfl_xor(sq[j], off);
            }
        }
        #pragma unroll
        for (int j = 0; j < 4; ++j) {
            float mu  = sm[j] * (1.f / 64.f);
            float var = sq[j] * (1.f / 64.f) - mu * mu;
            float rs  = rsqrtf(var + 1e-5f);
            #pragma unroll
            for (int nt = 0; nt < 4; ++nt)
                tw[fq * 4 + j][nt * 16 + fr] = (y2[nt][j] - mu) * rs * gam[nt] + bet[nt];
        }

        #pragma unroll
        for (int it = 0; it < 4; ++it) {
            int idx = it * 256 + lane * 4;
            *(float4*)(baseo + idx) = *(const float4*)&tw[idx >> 6][idx & 63];
        }
    }
}

template <int ALIGN>
static void run_csr(const int* rows, const int* cols, const float* vals,
                    const float* ini, float* out, char* w, int E, size_t packed_cap,
                    int nchunk, const float* Ws, const float* bs,
                    const float* gamma, const float* beta, hipStream_t stream) {
    size_t inibf_b  = (size_t)NN * 32 * 4;
    size_t e1bf_b   = inibf_b;
    size_t packed_b = packed_cap * 8;
    size_t rp_b     = (((size_t)NN + 1) * 4 + 63) & ~(size_t)63;
    size_t rpe_b    = (ALIGN > 1) ? rp_b : 0;
    size_t bsrt_b   = (((size_t)NBKT + 1) * 4 + 63) & ~(size_t)63;
    size_t pad_b    = (size_t)NBKT * CPAD * 4;

    unsigned* ini_bf   = (unsigned*)w;  w += inibf_b;
    unsigned* e1_bf    = (unsigned*)w;  w += e1bf_b;
    int2*     packed   = (int2*)w;      w += packed_b;
    int*      rp       = (int*)w;       w += rp_b;
    int*      rpe      = (ALIGN > 1) ? (int*)w : rp + 1;  w += rpe_b;
    int*      bktstart = (int*)w;       w += bsrt_b;
    int*      tot_p    = (int*)w;       w += pad_b;
    int*      cursor_p = (int*)w;

    int epb = (E + nchunk - 1) / nchunk;
    cvt_bf16<<<2048, 256, 0, stream>>>((const float2*)ini, ini_bf, NN * 32);
    zero_i<<<(NBKT * CPAD + 255) / 256, 256, 0, stream>>>(tot_p, NBKT * CPAD);
    bkt_count<ALIGN><<<nchunk, 1024, 0, stream>>>(rows, tot_p, E, epb);
    bkt_scan<<<1, 1024, 0, stream>>>(tot_p, bktstart, cursor_p);
    scatter_l1<ALIGN><<<nchunk, 1024, 0, stream>>>(rows, cols, vals, cursor_p, packed, E, epb);
    sort_l2<<<NBKT, 256, 0, stream>>>(bktstart, packed, rp, rpe);

    spmm_g<<<NTILE, 256, 0, stream>>>(rp, rpe, packed, (const uint2*)ini_bf,
                                      (uint2*)e1_bf, NN);
    spmm_g<<<NTILE, 256, 0, stream>>>(rp, rpe, packed, (const uint2*)e1_bf,
                                      (uint2*)ini_bf, NN);   // ini_bf dead after hop-1
    mlp_v2<1><<<1024, 256, 0, stream>>>((const uint2*)ini_bf, out, Ws, bs, gamma, beta);
}

extern "C" void kernel_launch(void* const* d_in, const int* in_sizes, int n_in,
                              void* d_out, int out_size, void* d_ws, size_t ws_size,
                              hipStream_t stream) {
    const int*   rows  = (const int*)d_in[0];
    const int*   cols  = (const int*)d_in[1];
    const float* vals  = (const float*)d_in[2];
    const float* ini   = (const float*)d_in[3];
    const float* Ws    = (const float*)d_in[4];
    const float* bs    = (const float*)d_in[5];
    const float* gamma = (const float*)d_in[6];
    const float* beta  = (const float*)d_in[7];
    float* out = (float*)d_out;
    int E = in_sizes[0];

    size_t inibf_b = (size_t)NN * 32 * 4;
    size_t rp_b    = (((size_t)NN + 1) * 4 + 63) & ~(size_t)63;
    size_t bsrt_b  = (((size_t)NBKT + 1) * 4 + 63) & ~(size_t)63;
    size_t pad_b   = (size_t)NBKT * CPAD * 4;
    auto cap  = [&](int nc) { return (size_t)E + (size_t)NBKT * nc * 7; };
    auto need = [&](int nc, int nrp) {
        return 2 * inibf_b + cap(nc) * 8 + (size_t)nrp * rp_b + bsrt_b + 2 * pad_b;
    };

    if (ws_size >= need(512, 2)) {
        run_csr<8>(rows, cols, vals, ini, out, (char*)d_ws, E, cap(512), 512,
                   Ws, bs, gamma, beta, stream);
    } else if (ws_size >= need(256, 2)) {
        run_csr<8>(rows, cols, vals, ini, out, (char*)d_ws, E, cap(256), 256,
                   Ws, bs, gamma, beta, stream);
    } else if (ws_size >= 2 * inibf_b + (size_t)E * 8 + rp_b + bsrt_b + 2 * pad_b) {
        run_csr<1>(rows, cols, vals, ini, out, (char*)d_ws, E, (size_t)E, 256,
                   Ws, bs, gamma, beta, stream);
    } else {
        float* e1 = (float*)d_ws;
        int n4 = out_size / 4;
        int zb = (n4 + 255) / 256;
        zero_f4<<<zb, 256, 0, stream>>>((float4*)e1,  n4);
        zero_f4<<<zb, 256, 0, stream>>>((float4*)out, n4);
        spmm_scatter<<<12800, 256, 0, stream>>>(rows, cols, vals, ini, e1, E);
        spmm_scatter<<<12800, 256, 0, stream>>>(rows, cols, vals, e1, out, E);
        mlp_v2<0><<<1024, 256, 0, stream>>>(nullptr, out, Ws, bs, gamma, beta);
    }
}